// Round 6
// baseline (640.873 us; speedup 1.0000x reference)
//
#include <hip/hip_runtime.h>
#include <hip/hip_bf16.h>

#define KDIM 1024
#define NDIM 1024
#define NEXP 8
#define TTOK 8192
#define NT (KDIM / 32)

typedef __bf16 bf16x8 __attribute__((ext_vector_type(8)));
typedef __bf16 bf16x4 __attribute__((ext_vector_type(4)));
typedef float  f32x4  __attribute__((ext_vector_type(4)));

__device__ __forceinline__ void gl2lds16(const void* g, void* l) {
  __builtin_amdgcn_global_load_lds(
      (const __attribute__((address_space(1))) void*)g,
      (__attribute__((address_space(3))) void*)l, 16, 0, 0);
}

// swB slot(e,panel,kt,lane) = W[e][kt*32 + (lane>>4)*8 .. +8][panel*16 + (lane&15)]

// ---------------- prepass: W transpose fp32 -> bf16 swizzled (W-only) ----------------
__global__ __launch_bounds__(256) void prepass_w(
    const float* __restrict__ W, __bf16* __restrict__ swB)
{
  __shared__ __align__(16) __bf16 Lt[64 * 72];
  const int t = threadIdx.x;
  int bid = blockIdx.x;
  int e = bid >> 8, r = bid & 255;
  int k0 = (r >> 4) * 64, n0 = (r & 15) * 64;
  const float* Wp = W + (size_t)e * KDIM * NDIM;
  int rr0 = t >> 4, c4 = t & 15;
#pragma unroll
  for (int p = 0; p < 4; ++p) {
    int kk = rr0 + p * 16;
    float4 v = *(const float4*)(Wp + (size_t)(k0 + kk) * NDIM + n0 + c4 * 4);
    Lt[(c4 * 4 + 0) * 72 + kk] = (__bf16)v.x;
    Lt[(c4 * 4 + 1) * 72 + kk] = (__bf16)v.y;
    Lt[(c4 * 4 + 2) * 72 + kk] = (__bf16)v.z;
    Lt[(c4 * 4 + 3) * 72 + kk] = (__bf16)v.w;
  }
  __syncthreads();
#pragma unroll
  for (int q = 0; q < 2; ++q) {
    int slot = q * 256 + t;
    int lane = slot & 63, grp = slot >> 6;
    int np = grp & 3, kt2 = grp >> 2;
    int nl = np * 16 + (lane & 15);
    int kl = kt2 * 32 + ((lane >> 4) << 3);
    bf16x8 v = *(const bf16x8*)(Lt + nl * 72 + kl);
    int panel = (n0 >> 4) + np;
    int ktg = (k0 >> 5) + kt2;
    size_t sg = (((size_t)e * 64 + panel) * 32 + ktg) * 64 + lane;
    *(bf16x8*)(swB + sg * 8) = v;
  }
}

// ---------------- GEMM: A direct-from-x, DEPTH-2 register pipeline, one wait/iter -------
// Round-4 failure: A had a depth-1 chain (wait A(kt+1) mid-iter -> issue A(kt+2) after);
// every iteration paid full L2-congested load latency (GEMM 111us, MfmaUtil 6.5%).
// Fix: A(kt+2) issued in iter kt into parity register buffer (R0/R1, unroll-2 static
// indexing), consumed at top of iter kt+2 -> 2 iterations of slack, matching the proven
// B protocol. Single wait point per iteration:
//   queue at top of iter kt: [A(kt):8][B(kt):2][A(kt+1):8][B(kt+1):2] = 20
//   vmcnt(10) retires exactly A(kt)+B(kt) (A issued before B everywhere);
//   convert A(kt)->aF; barrier (all waves' B(kt) now in LDS); issue A(kt+2)+B(kt+2);
//   sched_barrier(0) pins issues above the MFMA cluster; compute(kt).
//   Tail: no issues for kt+2>=NT; kt=NT-1 uses vmcnt(0).
// WAR: R-buffer consumed by convert before same-body reissue; LDS buf[(kt+2)%3]'s last
// readers ran compute(kt-1) which precedes barrier(kt) in every wave's program order.
__global__ __launch_bounds__(256, 3) void moe_gemm_lds(
    const float* __restrict__ x, const __bf16* __restrict__ swB,
    const int* __restrict__ gs, const float* __restrict__ bias,
    float* __restrict__ out)
{
  __shared__ __align__(16) __bf16 buf[3][4096];   // 3 x 8 KB (B only)

  const int b = blockIdx.x;
  const int xcd = b & 7, bi = b >> 3;
  int y = xcd * 9 + bi % 9;           // global m-tile index
  const int nt = bi / 9;

  int e = 0, tile0 = 0, lo = 0, hi = 0, found = 0, off = 0;
#pragma unroll
  for (int i = 0; i < NEXP; ++i) {
    int g = gs[i];
    int first = off >> 7;
    int cnt = (g > 0) ? (((off + g - 1) >> 7) - first + 1) : 0;
    if (!found) {
      if (y < cnt) {
        found = 1; e = i; tile0 = (first + y) << 7;
        lo = max(tile0, off); hi = min(tile0 + 128, off + g);
      } else y -= cnt;
    }
    off += g;
  }
  if (!found) return;                       // block-uniform: no barrier mismatch
  const int n0 = nt * 128;

  const int t = threadIdx.x, lane = t & 63, wv = t >> 6;
  const int wm = wv & 1, wn = wv >> 1, lm = lane & 15, lg = lane >> 4;

  // B staging: wave wv stages panels {wv, 4+wv} (panel stride = 32 kt * 512 = 16384 elems)
  const __bf16* gB0 = swB + (size_t)(e * 64 + (n0 >> 4) + wv) * 16384 + lane * 8;
  const __bf16* gB1 = swB + (size_t)(e * 64 + (n0 >> 4) + 4 + wv) * 16384 + lane * 8;

  auto stage_B = [&](int kt, int sb) {
    __bf16* l = &buf[sb][0];
    const int ko = kt * 512;
    gl2lds16(gB0 + ko, l + (size_t)(wv * 64) * 8);           // panel wv
    gl2lds16(gB1 + ko, l + (size_t)((4 + wv) * 64) * 8);     // panel 4+wv
  };

  // A direct loads: aF[i] <- x[tile0 + wm*64 + i*16 + lm][kt*32 + lg*8 .. +8]
  const float* xA = x + (size_t)(tile0 + wm * 64 + lm) * KDIM + lg * 8;
  auto issue_x = [&](int kt, float4 (&RR)[4][2]) {
#pragma unroll
    for (int i = 0; i < 4; ++i) {
      const float* p = xA + (size_t)(i * 16) * KDIM + kt * 32;
      RR[i][0] = *(const float4*)p;
      RR[i][1] = *(const float4*)(p + 4);
    }
  };
  bf16x8 aF[4];
  auto convert_x = [&](const float4 (&RR)[4][2]) {
#pragma unroll
    for (int i = 0; i < 4; ++i) {
      bf16x8 v;
      v[0] = (__bf16)RR[i][0].x; v[1] = (__bf16)RR[i][0].y;
      v[2] = (__bf16)RR[i][0].z; v[3] = (__bf16)RR[i][0].w;
      v[4] = (__bf16)RR[i][1].x; v[5] = (__bf16)RR[i][1].y;
      v[6] = (__bf16)RR[i][1].z; v[7] = (__bf16)RR[i][1].w;
      aF[i] = v;
    }
  };

  f32x4 acc[4][4] = {};
  auto compute = [&](const __bf16* l) {
    bf16x8 bF[4];
#pragma unroll
    for (int j = 0; j < 4; ++j)
      bF[j] = *(const bf16x8*)(l + (size_t)((wn * 4 + j) * 64 + lane) * 8);
#pragma unroll
    for (int i = 0; i < 4; ++i)
#pragma unroll
      for (int j = 0; j < 4; ++j)
        acc[i][j] = __builtin_amdgcn_mfma_f32_16x16x32_bf16(aF[i], bF[j], acc[i][j], 0, 0, 0);
  };

  float4 R0[4][2], R1[4][2];

  // prologue (A before B at every issue point keeps the retirement invariant):
  issue_x(0, R0);        // [A0:8]
  stage_B(0, 0);         // [A0:8][B0:2]
  issue_x(1, R1);        // [A0:8][B0:2][A1:8]
  stage_B(1, 1);         // [A0:8][B0:2][A1:8][B1:2] = 20 = steady-state invariant

#define BODY(kt, RR, WAITN)                                              \
  asm volatile("s_waitcnt vmcnt(" #WAITN ")" ::: "memory");              \
  convert_x(RR);                                                         \
  asm volatile("s_barrier" ::: "memory");                                \
  if ((kt) + 2 < NT) {                                                   \
    issue_x((kt) + 2, RR);                                               \
    stage_B((kt) + 2, ((kt) + 2) % 3);                                   \
  }                                                                      \
  __builtin_amdgcn_sched_barrier(0);                                     \
  compute(&buf[(kt) % 3][0]);

#pragma unroll 1
  for (int kt2 = 0; kt2 < NT - 2; kt2 += 2) {
    BODY(kt2, R0, 10);
    BODY(kt2 + 1, R1, 10);
  }
  BODY(NT - 2, R0, 10);   // kt=30: queue 20 -> wait retires A30+B30; no new issues
  BODY(NT - 1, R1, 0);    // kt=31: queue 10 -> drain; nothing left in flight
#undef BODY

  float bj[4];
#pragma unroll
  for (int j = 0; j < 4; ++j) bj[j] = bias[e * NDIM + n0 + wn * 64 + j * 16 + lm];
#pragma unroll
  for (int i = 0; i < 4; ++i)
#pragma unroll
    for (int r = 0; r < 4; ++r) {
      int rabs = tile0 + wm * 64 + i * 16 + lg * 4 + r;   // C/D: row = quad*4 + reg
      if (rabs >= lo && rabs < hi) {
#pragma unroll
        for (int j = 0; j < 4; ++j)
          out[(size_t)rabs * NDIM + n0 + wn * 64 + j * 16 + lm] = acc[i][j][r] + bj[j];
      }
    }
}

// ---------------- fallback (fp32 in-loop conversion) for small ws ----------------
#define LDA 40
__global__ __launch_bounds__(256) void moe_gemm_kernel(
    const float* __restrict__ x, const int* __restrict__ gs,
    const float* __restrict__ W, const float* __restrict__ bias,
    float* __restrict__ out)
{
  __shared__ __bf16 Al[128 * LDA];
  __shared__ __bf16 Bl[128 * LDA];
  const int e = blockIdx.z, mt = blockIdx.y, nt = blockIdx.x;
  int off = 0;
#pragma unroll
  for (int i = 0; i < NEXP; ++i) { int g = gs[i]; if (i < e) off += g; }
  const int ge = gs[e];
  const int m0 = mt * 128;
  if (m0 >= ge) return;
  const int rows = min(128, ge - m0);
  const int row0 = off + m0;
  const int n0 = nt * 128;
  const int t = threadIdx.x, lane = t & 63, wv = t >> 6;
  const int wm = wv & 1, wn = wv >> 1, lm = lane & 15, lg = lane >> 4;
  const int am = t >> 3, kq = t & 7, nb = t & 127, kh = t >> 7;
  float4 aReg[4]; float bReg[16];
  const float* Wp = W + (size_t)e * KDIM * NDIM + n0 + nb;
  auto load_tile = [&](int kt) {
#pragma unroll
    for (int p = 0; p < 4; ++p) {
      int r = am + 32 * p;
      if (r < rows) aReg[p] = *(const float4*)(x + (size_t)(row0 + r) * KDIM + kt * 32 + kq * 4);
      else aReg[p] = make_float4(0.f, 0.f, 0.f, 0.f);
    }
    const float* wp = Wp + (size_t)(kt * 32 + kh * 16) * NDIM;
#pragma unroll
    for (int j = 0; j < 16; ++j) bReg[j] = wp[(size_t)j * NDIM];
  };
  auto store_tile = [&]() {
#pragma unroll
    for (int p = 0; p < 4; ++p) {
      bf16x4 v;
      v[0] = (__bf16)aReg[p].x; v[1] = (__bf16)aReg[p].y;
      v[2] = (__bf16)aReg[p].z; v[3] = (__bf16)aReg[p].w;
      *(bf16x4*)(Al + (am + 32 * p) * LDA + kq * 4) = v;
    }
    bf16x8 b0, b1;
#pragma unroll
    for (int j = 0; j < 8; ++j) { b0[j] = (__bf16)bReg[j]; b1[j] = (__bf16)bReg[8 + j]; }
    *(bf16x8*)(Bl + nb * LDA + kh * 16) = b0;
    *(bf16x8*)(Bl + nb * LDA + kh * 16 + 8) = b1;
  };
  f32x4 acc[4][4] = {};
  load_tile(0);
#pragma unroll 1
  for (int kt = 0; kt < KDIM / 32; ++kt) {
    __syncthreads();
    store_tile();
    __syncthreads();
    if (kt + 1 < KDIM / 32) load_tile(kt + 1);
    bf16x8 af[4], bfr[4];
#pragma unroll
    for (int i = 0; i < 4; ++i)
      af[i] = *(const bf16x8*)(Al + (wm * 64 + i * 16 + lm) * LDA + lg * 8);
#pragma unroll
    for (int j = 0; j < 4; ++j)
      bfr[j] = *(const bf16x8*)(Bl + (wn * 64 + j * 16 + lm) * LDA + lg * 8);
#pragma unroll
    for (int i = 0; i < 4; ++i)
#pragma unroll
      for (int j = 0; j < 4; ++j)
        acc[i][j] = __builtin_amdgcn_mfma_f32_16x16x32_bf16(af[i], bfr[j], acc[i][j], 0, 0, 0);
  }
  float bj[4];
#pragma unroll
  for (int j = 0; j < 4; ++j) bj[j] = bias[e * NDIM + n0 + wn * 64 + j * 16 + lm];
#pragma unroll
  for (int i = 0; i < 4; ++i)
#pragma unroll
    for (int r = 0; r < 4; ++r) {
      int rr = wm * 64 + i * 16 + lg * 4 + r;
      if (rr < rows) {
#pragma unroll
        for (int j = 0; j < 4; ++j)
          out[(size_t)(row0 + rr) * NDIM + n0 + wn * 64 + j * 16 + lm] = acc[i][j][r] + bj[j];
      }
    }
}

extern "C" void kernel_launch(void* const* d_in, const int* in_sizes, int n_in,
                              void* d_out, int out_size, void* d_ws, size_t ws_size,
                              hipStream_t stream) {
  const float* x    = (const float*)d_in[0];
  const int*   gs   = (const int*)d_in[1];
  const float* W    = (const float*)d_in[2];
  const float* bias = (const float*)d_in[3];
  float*       out  = (float*)d_out;

  const size_t swB_bytes = (size_t)NEXP * KDIM * NDIM * 2;
  if (ws_size >= swB_bytes) {
    __bf16* swB = (__bf16*)d_ws;
    prepass_w<<<dim3(2048), 256, 0, stream>>>(W, swB);
    // 1D grid, XCD-contiguous m-ranges: xcd=b&7 owns m-tiles [9*xcd, 9*xcd+9) x all n.
    moe_gemm_lds<<<dim3(576), 256, 0, stream>>>(x, swB, gs, bias, out);
  } else {
    moe_gemm_kernel<<<dim3(NDIM / 128, TTOK / 128, NEXP), 256, 0, stream>>>(x, gs, W, bias, out);
  }
}

// Round 7
// 220.642 us; speedup vs baseline: 2.9046x; 2.9046x over previous
//
#include <hip/hip_runtime.h>
#include <hip/hip_bf16.h>

#define KDIM 1024
#define NDIM 1024
#define NEXP 8
#define TTOK 8192
#define NT (KDIM / 32)

typedef __bf16 bf16x8 __attribute__((ext_vector_type(8)));
typedef __bf16 bf16x4 __attribute__((ext_vector_type(4)));
typedef float  f32x4  __attribute__((ext_vector_type(4)));

__device__ __forceinline__ void gl2lds16(const void* g, void* l) {
  __builtin_amdgcn_global_load_lds(
      (const __attribute__((address_space(1))) void*)g,
      (__attribute__((address_space(3))) void*)l, 16, 0, 0);
}

// swB slot(e,panel,kt,lane) = W[e][kt*32 + (lane>>4)*8 .. +8][panel*16 + (lane&15)]

// ---------------- prepass: W transpose fp32 -> bf16 swizzled (W-only) ----------------
__global__ __launch_bounds__(256) void prepass_w(
    const float* __restrict__ W, __bf16* __restrict__ swB)
{
  __shared__ __align__(16) __bf16 Lt[64 * 72];
  const int t = threadIdx.x;
  int bid = blockIdx.x;
  int e = bid >> 8, r = bid & 255;
  int k0 = (r >> 4) * 64, n0 = (r & 15) * 64;
  const float* Wp = W + (size_t)e * KDIM * NDIM;
  int rr0 = t >> 4, c4 = t & 15;
#pragma unroll
  for (int p = 0; p < 4; ++p) {
    int kk = rr0 + p * 16;
    float4 v = *(const float4*)(Wp + (size_t)(k0 + kk) * NDIM + n0 + c4 * 4);
    Lt[(c4 * 4 + 0) * 72 + kk] = (__bf16)v.x;
    Lt[(c4 * 4 + 1) * 72 + kk] = (__bf16)v.y;
    Lt[(c4 * 4 + 2) * 72 + kk] = (__bf16)v.z;
    Lt[(c4 * 4 + 3) * 72 + kk] = (__bf16)v.w;
  }
  __syncthreads();
#pragma unroll
  for (int q = 0; q < 2; ++q) {
    int slot = q * 256 + t;
    int lane = slot & 63, grp = slot >> 6;
    int np = grp & 3, kt2 = grp >> 2;
    int nl = np * 16 + (lane & 15);
    int kl = kt2 * 32 + ((lane >> 4) << 3);
    bf16x8 v = *(const bf16x8*)(Lt + nl * 72 + kl);
    int panel = (n0 >> 4) + np;
    int ktg = (k0 >> 5) + kt2;
    size_t sg = (((size_t)e * 64 + panel) * 32 + ktg) * 64 + lane;
    *(bf16x8*)(swB + sg * 8) = v;
  }
}

// ---------------- GEMM: A direct-from-x, DEPTH-2 register pipeline, one wait/iter -------
// Round-6 failure: demand (acc 64 AGPR + 2x32 R + 16 aF + 16 bF + addr ~ 180 unified regs)
// exceeded the ~170-reg budget implied by __launch_bounds__(256,3) -> the allocator
// spilled an R buffer to scratch: FETCH 716 MB / WRITE 1.31 GB (~144 B/thread/iter of
// spill re-read), GEMM 553us. Fix: __launch_bounds__(256,2) -> ~256-reg budget, depth-2
// pipeline fully in registers. 2 blocks/CU; latency hidden by ~2 iters of pipeline slack.
//   queue at top of iter kt: [A(kt):8][B(kt):2][A(kt+1):8][B(kt+1):2] = 20
//   vmcnt(10) retires exactly A(kt)+B(kt) (A issued before B everywhere);
//   convert A(kt)->aF; barrier (all waves' B(kt) now in LDS); issue A(kt+2)+B(kt+2);
//   sched_barrier(0) pins issues above the MFMA cluster; compute(kt).
//   Tail: no issues for kt+2>=NT; kt=NT-1 uses vmcnt(0).
// WAR: R-buffer consumed by convert before same-body reissue; LDS buf[(kt+2)%3]'s last
// readers ran compute(kt-1) which precedes barrier(kt) in every wave's program order.
__global__ __launch_bounds__(256, 2) void moe_gemm_lds(
    const float* __restrict__ x, const __bf16* __restrict__ swB,
    const int* __restrict__ gs, const float* __restrict__ bias,
    float* __restrict__ out)
{
  __shared__ __align__(16) __bf16 buf[3][4096];   // 3 x 8 KB (B only)

  const int b = blockIdx.x;
  const int xcd = b & 7, bi = b >> 3;
  int y = xcd * 9 + bi % 9;           // global m-tile index
  const int nt = bi / 9;

  int e = 0, tile0 = 0, lo = 0, hi = 0, found = 0, off = 0;
#pragma unroll
  for (int i = 0; i < NEXP; ++i) {
    int g = gs[i];
    int first = off >> 7;
    int cnt = (g > 0) ? (((off + g - 1) >> 7) - first + 1) : 0;
    if (!found) {
      if (y < cnt) {
        found = 1; e = i; tile0 = (first + y) << 7;
        lo = max(tile0, off); hi = min(tile0 + 128, off + g);
      } else y -= cnt;
    }
    off += g;
  }
  if (!found) return;                       // block-uniform: no barrier mismatch
  const int n0 = nt * 128;

  const int t = threadIdx.x, lane = t & 63, wv = t >> 6;
  const int wm = wv & 1, wn = wv >> 1, lm = lane & 15, lg = lane >> 4;

  // B staging: wave wv stages panels {wv, 4+wv} (panel stride = 32 kt * 512 = 16384 elems)
  const __bf16* gB0 = swB + (size_t)(e * 64 + (n0 >> 4) + wv) * 16384 + lane * 8;
  const __bf16* gB1 = swB + (size_t)(e * 64 + (n0 >> 4) + 4 + wv) * 16384 + lane * 8;

  auto stage_B = [&](int kt, int sb) {
    __bf16* l = &buf[sb][0];
    const int ko = kt * 512;
    gl2lds16(gB0 + ko, l + (size_t)(wv * 64) * 8);           // panel wv
    gl2lds16(gB1 + ko, l + (size_t)((4 + wv) * 64) * 8);     // panel 4+wv
  };

  // A direct loads: aF[i] <- x[tile0 + wm*64 + i*16 + lm][kt*32 + lg*8 .. +8]
  const float* xA = x + (size_t)(tile0 + wm * 64 + lm) * KDIM + lg * 8;
  auto issue_x = [&](int kt, float4 (&RR)[4][2]) {
#pragma unroll
    for (int i = 0; i < 4; ++i) {
      const float* p = xA + (size_t)(i * 16) * KDIM + kt * 32;
      RR[i][0] = *(const float4*)p;
      RR[i][1] = *(const float4*)(p + 4);
    }
  };
  bf16x8 aF[4];
  auto convert_x = [&](const float4 (&RR)[4][2]) {
#pragma unroll
    for (int i = 0; i < 4; ++i) {
      bf16x8 v;
      v[0] = (__bf16)RR[i][0].x; v[1] = (__bf16)RR[i][0].y;
      v[2] = (__bf16)RR[i][0].z; v[3] = (__bf16)RR[i][0].w;
      v[4] = (__bf16)RR[i][1].x; v[5] = (__bf16)RR[i][1].y;
      v[6] = (__bf16)RR[i][1].z; v[7] = (__bf16)RR[i][1].w;
      aF[i] = v;
    }
  };

  f32x4 acc[4][4] = {};
  auto compute = [&](const __bf16* l) {
    bf16x8 bF[4];
#pragma unroll
    for (int j = 0; j < 4; ++j)
      bF[j] = *(const bf16x8*)(l + (size_t)((wn * 4 + j) * 64 + lane) * 8);
#pragma unroll
    for (int i = 0; i < 4; ++i)
#pragma unroll
      for (int j = 0; j < 4; ++j)
        acc[i][j] = __builtin_amdgcn_mfma_f32_16x16x32_bf16(aF[i], bF[j], acc[i][j], 0, 0, 0);
  };

  float4 R0[4][2], R1[4][2];

  // prologue (A before B at every issue point keeps the retirement invariant):
  issue_x(0, R0);        // [A0:8]
  stage_B(0, 0);         // [A0:8][B0:2]
  issue_x(1, R1);        // [A0:8][B0:2][A1:8]
  stage_B(1, 1);         // [A0:8][B0:2][A1:8][B1:2] = 20 = steady-state invariant

#define BODY(kt, RR, WAITN)                                              \
  asm volatile("s_waitcnt vmcnt(" #WAITN ")" ::: "memory");              \
  convert_x(RR);                                                         \
  asm volatile("s_barrier" ::: "memory");                                \
  if ((kt) + 2 < NT) {                                                   \
    issue_x((kt) + 2, RR);                                               \
    stage_B((kt) + 2, ((kt) + 2) % 3);                                   \
  }                                                                      \
  __builtin_amdgcn_sched_barrier(0);                                     \
  compute(&buf[(kt) % 3][0]);

#pragma unroll 1
  for (int kt2 = 0; kt2 < NT - 2; kt2 += 2) {
    BODY(kt2, R0, 10);
    BODY(kt2 + 1, R1, 10);
  }
  BODY(NT - 2, R0, 10);   // kt=30: queue 20 -> wait retires A30+B30; no new issues
  BODY(NT - 1, R1, 0);    // kt=31: queue 10 -> drain; nothing left in flight
#undef BODY

  float bj[4];
#pragma unroll
  for (int j = 0; j < 4; ++j) bj[j] = bias[e * NDIM + n0 + wn * 64 + j * 16 + lm];
#pragma unroll
  for (int i = 0; i < 4; ++i)
#pragma unroll
    for (int r = 0; r < 4; ++r) {
      int rabs = tile0 + wm * 64 + i * 16 + lg * 4 + r;   // C/D: row = quad*4 + reg
      if (rabs >= lo && rabs < hi) {
#pragma unroll
        for (int j = 0; j < 4; ++j)
          out[(size_t)rabs * NDIM + n0 + wn * 64 + j * 16 + lm] = acc[i][j][r] + bj[j];
      }
    }
}

// ---------------- fallback (fp32 in-loop conversion) for small ws ----------------
#define LDA 40
__global__ __launch_bounds__(256) void moe_gemm_kernel(
    const float* __restrict__ x, const int* __restrict__ gs,
    const float* __restrict__ W, const float* __restrict__ bias,
    float* __restrict__ out)
{
  __shared__ __bf16 Al[128 * LDA];
  __shared__ __bf16 Bl[128 * LDA];
  const int e = blockIdx.z, mt = blockIdx.y, nt = blockIdx.x;
  int off = 0;
#pragma unroll
  for (int i = 0; i < NEXP; ++i) { int g = gs[i]; if (i < e) off += g; }
  const int ge = gs[e];
  const int m0 = mt * 128;
  if (m0 >= ge) return;
  const int rows = min(128, ge - m0);
  const int row0 = off + m0;
  const int n0 = nt * 128;
  const int t = threadIdx.x, lane = t & 63, wv = t >> 6;
  const int wm = wv & 1, wn = wv >> 1, lm = lane & 15, lg = lane >> 4;
  const int am = t >> 3, kq = t & 7, nb = t & 127, kh = t >> 7;
  float4 aReg[4]; float bReg[16];
  const float* Wp = W + (size_t)e * KDIM * NDIM + n0 + nb;
  auto load_tile = [&](int kt) {
#pragma unroll
    for (int p = 0; p < 4; ++p) {
      int r = am + 32 * p;
      if (r < rows) aReg[p] = *(const float4*)(x + (size_t)(row0 + r) * KDIM + kt * 32 + kq * 4);
      else aReg[p] = make_float4(0.f, 0.f, 0.f, 0.f);
    }
    const float* wp = Wp + (size_t)(kt * 32 + kh * 16) * NDIM;
#pragma unroll
    for (int j = 0; j < 16; ++j) bReg[j] = wp[(size_t)j * NDIM];
  };
  auto store_tile = [&]() {
#pragma unroll
    for (int p = 0; p < 4; ++p) {
      bf16x4 v;
      v[0] = (__bf16)aReg[p].x; v[1] = (__bf16)aReg[p].y;
      v[2] = (__bf16)aReg[p].z; v[3] = (__bf16)aReg[p].w;
      *(bf16x4*)(Al + (am + 32 * p) * LDA + kq * 4) = v;
    }
    bf16x8 b0, b1;
#pragma unroll
    for (int j = 0; j < 8; ++j) { b0[j] = (__bf16)bReg[j]; b1[j] = (__bf16)bReg[8 + j]; }
    *(bf16x8*)(Bl + nb * LDA + kh * 16) = b0;
    *(bf16x8*)(Bl + nb * LDA + kh * 16 + 8) = b1;
  };
  f32x4 acc[4][4] = {};
  load_tile(0);
#pragma unroll 1
  for (int kt = 0; kt < KDIM / 32; ++kt) {
    __syncthreads();
    store_tile();
    __syncthreads();
    if (kt + 1 < KDIM / 32) load_tile(kt + 1);
    bf16x8 af[4], bfr[4];
#pragma unroll
    for (int i = 0; i < 4; ++i)
      af[i] = *(const bf16x8*)(Al + (wm * 64 + i * 16 + lm) * LDA + lg * 8);
#pragma unroll
    for (int j = 0; j < 4; ++j)
      bfr[j] = *(const bf16x8*)(Bl + (wn * 64 + j * 16 + lm) * LDA + lg * 8);
#pragma unroll
    for (int i = 0; i < 4; ++i)
#pragma unroll
      for (int j = 0; j < 4; ++j)
        acc[i][j] = __builtin_amdgcn_mfma_f32_16x16x32_bf16(af[i], bfr[j], acc[i][j], 0, 0, 0);
  }
  float bj[4];
#pragma unroll
  for (int j = 0; j < 4; ++j) bj[j] = bias[e * NDIM + n0 + wn * 64 + j * 16 + lm];
#pragma unroll
  for (int i = 0; i < 4; ++i)
#pragma unroll
    for (int r = 0; r < 4; ++r) {
      int rr = wm * 64 + i * 16 + lg * 4 + r;
      if (rr < rows) {
#pragma unroll
        for (int j = 0; j < 4; ++j)
          out[(size_t)(row0 + rr) * NDIM + n0 + wn * 64 + j * 16 + lm] = acc[i][j][r] + bj[j];
      }
    }
}

extern "C" void kernel_launch(void* const* d_in, const int* in_sizes, int n_in,
                              void* d_out, int out_size, void* d_ws, size_t ws_size,
                              hipStream_t stream) {
  const float* x    = (const float*)d_in[0];
  const int*   gs   = (const int*)d_in[1];
  const float* W    = (const float*)d_in[2];
  const float* bias = (const float*)d_in[3];
  float*       out  = (float*)d_out;

  const size_t swB_bytes = (size_t)NEXP * KDIM * NDIM * 2;
  if (ws_size >= swB_bytes) {
    __bf16* swB = (__bf16*)d_ws;
    prepass_w<<<dim3(2048), 256, 0, stream>>>(W, swB);
    // 1D grid, XCD-contiguous m-ranges: xcd=b&7 owns m-tiles [9*xcd, 9*xcd+9) x all n.
    moe_gemm_lds<<<dim3(576), 256, 0, stream>>>(x, swB, gs, bias, out);
  } else {
    moe_gemm_kernel<<<dim3(NDIM / 128, TTOK / 128, NEXP), 256, 0, stream>>>(x, gs, W, bias, out);
  }
}

// Round 8
// 155.903 us; speedup vs baseline: 4.1107x; 1.4152x over previous
//
#include <hip/hip_runtime.h>
#include <hip/hip_bf16.h>

#define KDIM 1024
#define NDIM 1024
#define NEXP 8
#define TTOK 8192
#define NT (KDIM / 32)

typedef __bf16 bf16x8 __attribute__((ext_vector_type(8)));
typedef __bf16 bf16x4 __attribute__((ext_vector_type(4)));
typedef float  f32x4  __attribute__((ext_vector_type(4)));

__device__ __forceinline__ void gl2lds16(const void* g, void* l) {
  __builtin_amdgcn_global_load_lds(
      (const __attribute__((address_space(1))) void*)g,
      (__attribute__((address_space(3))) void*)l, 16, 0, 0);
}

// swB slot(e,panel,kt,lane) = W[e][kt*32 + (lane>>4)*8 .. +8][panel*16 + (lane&15)]

// ---------------- prepass: W transpose fp32 -> bf16 swizzled (W-only) ----------------
__global__ __launch_bounds__(256) void prepass_w(
    const float* __restrict__ W, __bf16* __restrict__ swB)
{
  __shared__ __align__(16) __bf16 Lt[64 * 72];
  const int t = threadIdx.x;
  int bid = blockIdx.x;
  int e = bid >> 8, r = bid & 255;
  int k0 = (r >> 4) * 64, n0 = (r & 15) * 64;
  const float* Wp = W + (size_t)e * KDIM * NDIM;
  int rr0 = t >> 4, c4 = t & 15;
#pragma unroll
  for (int p = 0; p < 4; ++p) {
    int kk = rr0 + p * 16;
    float4 v = *(const float4*)(Wp + (size_t)(k0 + kk) * NDIM + n0 + c4 * 4);
    Lt[(c4 * 4 + 0) * 72 + kk] = (__bf16)v.x;
    Lt[(c4 * 4 + 1) * 72 + kk] = (__bf16)v.y;
    Lt[(c4 * 4 + 2) * 72 + kk] = (__bf16)v.z;
    Lt[(c4 * 4 + 3) * 72 + kk] = (__bf16)v.w;
  }
  __syncthreads();
#pragma unroll
  for (int q = 0; q < 2; ++q) {
    int slot = q * 256 + t;
    int lane = slot & 63, grp = slot >> 6;
    int np = grp & 3, kt2 = grp >> 2;
    int nl = np * 16 + (lane & 15);
    int kl = kt2 * 32 + ((lane >> 4) << 3);
    bf16x8 v = *(const bf16x8*)(Lt + nl * 72 + kl);
    int panel = (n0 >> 4) + np;
    int ktg = (k0 >> 5) + kt2;
    size_t sg = (((size_t)e * 64 + panel) * 32 + ktg) * 64 + lane;
    *(bf16x8*)(swB + sg * 8) = v;
  }
}

// ------- GEMM: A fp32 staged from x via PRE-SWIZZLED-SOURCE gl2lds; m97 drain protocol -------
// Lessons (r4-r7): reg-staged A fails 4 ways; the latency hider in a barrier-per-K structure
// is INTER-BLOCK overlap (>=3 blocks/CU, m97/m114), not intra-wave slack. So: A staged by
// gl2lds (zero registers), 2x(A 16KB fp32 + B 8KB bf16) = 48KB -> 3 blocks/CU.
// Pre-swizzled source (m173): per-lane GLOBAL addr carries the fragment layout; LDS dest is
// wave-uniform base (HW adds lane*16). A slot: As[sb][h][p][lane] <- x[tile0+p*16+(lane&15)]
//                                                                    [kt*32+(lane>>4)*8+h*4..+4]
// ds_read: lane-linear 16B (conflict-free); convert f32->bf16 in-loop (same rounding as before).
// Protocol per iter: vmcnt(0) [stage(kt) landed]; s_barrier; stage(kt+1) [overlaps compute];
// compute(kt). Single barrier/iter is sufficient: a wave passes barrier(kt+1) only after
// issuing compute(kt)'s MFMAs, which required its buf[kt&1] ds_reads complete -> stage(kt+2)
// (issued after barrier(kt+1)) cannot overwrite live data.
__global__ __launch_bounds__(256, 3) void moe_gemm_lds(
    const float* __restrict__ x, const __bf16* __restrict__ swB,
    const int* __restrict__ gs, const float* __restrict__ bias,
    float* __restrict__ out)
{
  __shared__ __align__(16) float  As[2][2][8][64][4];   // [sb][h][panel][lane][4f] = 32 KB
  __shared__ __align__(16) __bf16 Bs[2][4096];          // [sb][slots] = 16 KB

  const int b = blockIdx.x;
  const int xcd = b & 7, bi = b >> 3;
  int y = xcd * 9 + bi % 9;           // global m-tile index
  const int nt = bi / 9;

  int e = 0, tile0 = 0, lo = 0, hi = 0, found = 0, off = 0;
#pragma unroll
  for (int i = 0; i < NEXP; ++i) {
    int g = gs[i];
    int first = off >> 7;
    int cnt = (g > 0) ? (((off + g - 1) >> 7) - first + 1) : 0;
    if (!found) {
      if (y < cnt) {
        found = 1; e = i; tile0 = (first + y) << 7;
        lo = max(tile0, off); hi = min(tile0 + 128, off + g);
      } else y -= cnt;
    }
    off += g;
  }
  if (!found) return;                       // block-uniform: no barrier mismatch
  const int n0 = nt * 128;

  const int t = threadIdx.x, lane = t & 63, wv = t >> 6;
  const int wm = wv & 1, wn = wv >> 1, lm = lane & 15, lg = lane >> 4;

  // B staging sources: wave wv stages panels {wv, 4+wv} (panel stride = 16384 elems)
  const __bf16* gB0 = swB + (size_t)(e * 64 + (n0 >> 4) + wv) * 16384 + lane * 8;
  const __bf16* gB1 = swB + (size_t)(e * 64 + (n0 >> 4) + 4 + wv) * 16384 + lane * 8;

  // A swizzled per-lane source base: row = tile0 + p*16 + lm, col = kt*32 + lg*8 + h*4
  const float* gA = x + (size_t)(tile0 + lm) * KDIM + (lg << 3);

  auto stage = [&](int kt, int sb) {
    // A: wave wv stages panels {wv, 4+wv} x halves {0,1}  (4 gl2lds, 1 KB each)
#pragma unroll
    for (int pp = 0; pp < 2; ++pp) {
      int p = wv + pp * 4;
      const float* s = gA + (size_t)(p * 16) * KDIM + kt * 32;
      gl2lds16(s,     &As[sb][0][p][0][0]);   // dest wave-uniform; HW adds lane*16
      gl2lds16(s + 4, &As[sb][1][p][0][0]);
    }
    // B: wave wv stages panels {wv, 4+wv}  (2 gl2lds)
    const int ko = kt * 512;
    gl2lds16(gB0 + ko, &Bs[sb][(size_t)(wv * 64) * 8]);
    gl2lds16(gB1 + ko, &Bs[sb][(size_t)((4 + wv) * 64) * 8]);
  };

  f32x4 acc[4][4] = {};
  auto compute = [&](int sb) {
    bf16x8 aF[4], bF[4];
#pragma unroll
    for (int i = 0; i < 4; ++i) {
      int p = wm * 4 + i;
      float4 lo4 = *(const float4*)&As[sb][0][p][lane][0];
      float4 hi4 = *(const float4*)&As[sb][1][p][lane][0];
      bf16x8 v;
      v[0] = (__bf16)lo4.x; v[1] = (__bf16)lo4.y; v[2] = (__bf16)lo4.z; v[3] = (__bf16)lo4.w;
      v[4] = (__bf16)hi4.x; v[5] = (__bf16)hi4.y; v[6] = (__bf16)hi4.z; v[7] = (__bf16)hi4.w;
      aF[i] = v;
    }
#pragma unroll
    for (int j = 0; j < 4; ++j)
      bF[j] = *(const bf16x8*)(&Bs[sb][0] + (size_t)((wn * 4 + j) * 64 + lane) * 8);
#pragma unroll
    for (int i = 0; i < 4; ++i)
#pragma unroll
      for (int j = 0; j < 4; ++j)
        acc[i][j] = __builtin_amdgcn_mfma_f32_16x16x32_bf16(aF[i], bF[j], acc[i][j], 0, 0, 0);
  };

  stage(0, 0);
#pragma unroll 1
  for (int kt = 0; kt < NT; ++kt) {
    asm volatile("s_waitcnt vmcnt(0)" ::: "memory");   // stage(kt) landed in buf[kt&1]
    asm volatile("s_barrier" ::: "memory");            // all waves: slice kt published
    if (kt + 1 < NT) stage(kt + 1, (kt + 1) & 1);      // overlaps compute(kt)
    compute(kt & 1);
  }

  float bj[4];
#pragma unroll
  for (int j = 0; j < 4; ++j) bj[j] = bias[e * NDIM + n0 + wn * 64 + j * 16 + lm];
#pragma unroll
  for (int i = 0; i < 4; ++i)
#pragma unroll
    for (int r = 0; r < 4; ++r) {
      int rabs = tile0 + wm * 64 + i * 16 + lg * 4 + r;   // C/D: row = quad*4 + reg
      if (rabs >= lo && rabs < hi) {
#pragma unroll
        for (int j = 0; j < 4; ++j)
          out[(size_t)rabs * NDIM + n0 + wn * 64 + j * 16 + lm] = acc[i][j][r] + bj[j];
      }
    }
}

// ---------------- fallback (fp32 in-loop conversion) for small ws ----------------
#define LDA 40
__global__ __launch_bounds__(256) void moe_gemm_kernel(
    const float* __restrict__ x, const int* __restrict__ gs,
    const float* __restrict__ W, const float* __restrict__ bias,
    float* __restrict__ out)
{
  __shared__ __bf16 Al[128 * LDA];
  __shared__ __bf16 Bl[128 * LDA];
  const int e = blockIdx.z, mt = blockIdx.y, nt = blockIdx.x;
  int off = 0;
#pragma unroll
  for (int i = 0; i < NEXP; ++i) { int g = gs[i]; if (i < e) off += g; }
  const int ge = gs[e];
  const int m0 = mt * 128;
  if (m0 >= ge) return;
  const int rows = min(128, ge - m0);
  const int row0 = off + m0;
  const int n0 = nt * 128;
  const int t = threadIdx.x, lane = t & 63, wv = t >> 6;
  const int wm = wv & 1, wn = wv >> 1, lm = lane & 15, lg = lane >> 4;
  const int am = t >> 3, kq = t & 7, nb = t & 127, kh = t >> 7;
  float4 aReg[4]; float bReg[16];
  const float* Wp = W + (size_t)e * KDIM * NDIM + n0 + nb;
  auto load_tile = [&](int kt) {
#pragma unroll
    for (int p = 0; p < 4; ++p) {
      int r = am + 32 * p;
      if (r < rows) aReg[p] = *(const float4*)(x + (size_t)(row0 + r) * KDIM + kt * 32 + kq * 4);
      else aReg[p] = make_float4(0.f, 0.f, 0.f, 0.f);
    }
    const float* wp = Wp + (size_t)(kt * 32 + kh * 16) * NDIM;
#pragma unroll
    for (int j = 0; j < 16; ++j) bReg[j] = wp[(size_t)j * NDIM];
  };
  auto store_tile = [&]() {
#pragma unroll
    for (int p = 0; p < 4; ++p) {
      bf16x4 v;
      v[0] = (__bf16)aReg[p].x; v[1] = (__bf16)aReg[p].y;
      v[2] = (__bf16)aReg[p].z; v[3] = (__bf16)aReg[p].w;
      *(bf16x4*)(Al + (am + 32 * p) * LDA + kq * 4) = v;
    }
    bf16x8 b0, b1;
#pragma unroll
    for (int j = 0; j < 8; ++j) { b0[j] = (__bf16)bReg[j]; b1[j] = (__bf16)bReg[8 + j]; }
    *(bf16x8*)(Bl + nb * LDA + kh * 16) = b0;
    *(bf16x8*)(Bl + nb * LDA + kh * 16 + 8) = b1;
  };
  f32x4 acc[4][4] = {};
  load_tile(0);
#pragma unroll 1
  for (int kt = 0; kt < KDIM / 32; ++kt) {
    __syncthreads();
    store_tile();
    __syncthreads();
    if (kt + 1 < KDIM / 32) load_tile(kt + 1);
    bf16x8 af[4], bfr[4];
#pragma unroll
    for (int i = 0; i < 4; ++i)
      af[i] = *(const bf16x8*)(Al + (wm * 64 + i * 16 + lm) * LDA + lg * 8);
#pragma unroll
    for (int j = 0; j < 4; ++j)
      bfr[j] = *(const bf16x8*)(Bl + (wn * 64 + j * 16 + lm) * LDA + lg * 8);
#pragma unroll
    for (int i = 0; i < 4; ++i)
#pragma unroll
      for (int j = 0; j < 4; ++j)
        acc[i][j] = __builtin_amdgcn_mfma_f32_16x16x32_bf16(af[i], bfr[j], acc[i][j], 0, 0, 0);
  }
  float bj[4];
#pragma unroll
  for (int j = 0; j < 4; ++j) bj[j] = bias[e * NDIM + n0 + wn * 64 + j * 16 + lm];
#pragma unroll
  for (int i = 0; i < 4; ++i)
#pragma unroll
    for (int r = 0; r < 4; ++r) {
      int rr = wm * 64 + i * 16 + lg * 4 + r;
      if (rr < rows) {
#pragma unroll
        for (int j = 0; j < 4; ++j)
          out[(size_t)(row0 + rr) * NDIM + n0 + wn * 64 + j * 16 + lm] = acc[i][j][r] + bj[j];
      }
    }
}

extern "C" void kernel_launch(void* const* d_in, const int* in_sizes, int n_in,
                              void* d_out, int out_size, void* d_ws, size_t ws_size,
                              hipStream_t stream) {
  const float* x    = (const float*)d_in[0];
  const int*   gs   = (const int*)d_in[1];
  const float* W    = (const float*)d_in[2];
  const float* bias = (const float*)d_in[3];
  float*       out  = (float*)d_out;

  const size_t swB_bytes = (size_t)NEXP * KDIM * NDIM * 2;
  if (ws_size >= swB_bytes) {
    __bf16* swB = (__bf16*)d_ws;
    prepass_w<<<dim3(2048), 256, 0, stream>>>(W, swB);
    // 1D grid, XCD-contiguous m-ranges: xcd=b&7 owns m-tiles [9*xcd, 9*xcd+9) x all n.
    moe_gemm_lds<<<dim3(576), 256, 0, stream>>>(x, swB, gs, bias, out);
  } else {
    moe_gemm_kernel<<<dim3(NDIM / 128, TTOK / 128, NEXP), 256, 0, stream>>>(x, gs, W, bias, out);
  }
}